// Round 15
// baseline (398.511 us; speedup 1.0000x reference)
//
#include <hip/hip_runtime.h>
#include <hip/hip_fp16.h>
#include <stdint.h>

typedef int v4i __attribute__((ext_vector_type(4)));

#define GLOAD_LDS16(g, l) __builtin_amdgcn_global_load_lds(                  \
    (const __attribute__((address_space(1))) void*)(g),                      \
    (__attribute__((address_space(3))) void*)(l), 16, 0, 0)

// workspace layout (bytes)
#define XQ_OFF 0u
#define XS_OFF 33554432u              // M*K int8
#define W8_OFF 33570816u              // + M*2 fp16 scales

// ---------------------------------------------------------------------------
// Self-classification of input delivery: x widened fp16->f32 has low 13
// mantissa bits zero; w widened int8->int32 has every word in [-128,127].
// ---------------------------------------------------------------------------
__device__ inline bool x_is_f32(const void* xin) {
  const uint32_t* xw = (const uint32_t*)xin;
  bool ok = true;
  #pragma unroll
  for (int i = 0; i < 16; ++i) ok &= ((xw[i] & 0x1FFFu) == 0u);
  return ok;
}
__device__ inline bool w_is_i32(const void* win) {
  const int* wi = (const int*)win;
  bool ok = true;
  #pragma unroll
  for (int i = 0; i < 16; ++i) ok &= (wi[i] >= -128 && wi[i] <= 127);
  return ok;
}

// ---------------------------------------------------------------------------
// Fused prologue: blocks [0, M) quant x rows; blocks [M, M+RW_BLOCKS) repack w.
// ---------------------------------------------------------------------------
#define RW_BLOCKS 1024

__global__ __launch_bounds__(256) void prologue(
    const void* __restrict__ xin, const void* __restrict__ win,
    int8_t* __restrict__ xq, __half* __restrict__ xs,
    int8_t* __restrict__ w8, int K, int M, int wtotal)
{
  const int tid = threadIdx.x;

  if (blockIdx.x >= (unsigned)M) {
    const bool as32 = w_is_i32(win);
    const int bid  = blockIdx.x - M;
    const int gtid = bid * 256 + tid;
    const int nthr = RW_BLOCKS * 256;
    if (as32) {
      const int4* w4 = (const int4*)win;
      uint32_t* dst = (uint32_t*)w8;
      const int n4 = wtotal >> 2;
      for (int i = gtid; i < n4; i += nthr) {
        int4 v = w4[i];
        dst[i] = (uint32_t)(v.x & 255) | ((uint32_t)(v.y & 255) << 8) |
                 ((uint32_t)(v.z & 255) << 16) | ((uint32_t)(v.w & 255) << 24);
      }
    } else {
      const uint4* src = (const uint4*)win;
      uint4* dst = (uint4*)w8;
      const int n16 = wtotal >> 4;
      for (int i = gtid; i < n16; i += nthr) dst[i] = src[i];
    }
    return;
  }

  const bool xf32 = x_is_f32(xin);
  const int row  = blockIdx.x;
  const int lane = tid & 63;
  const int wv   = tid >> 6;
  const size_t base = (size_t)row * (size_t)K;
  __shared__ float wmax[4];

  if (xf32 && K == 4096) {
    const float4* x4 = (const float4*)((const float*)xin + base);
    float4 v[4];
    #pragma unroll
    for (int i = 0; i < 4; ++i) v[i] = x4[i * 256 + tid];
    float mx = 0.0f;
    #pragma unroll
    for (int i = 0; i < 4; ++i)
      mx = fmaxf(mx, fmaxf(fmaxf(fabsf(v[i].x), fabsf(v[i].y)),
                           fmaxf(fabsf(v[i].z), fabsf(v[i].w))));
    #pragma unroll
    for (int off = 32; off; off >>= 1) mx = fmaxf(mx, __shfl_xor(mx, off, 64));
    if (lane == 0) wmax[wv] = mx;
    __syncthreads();
    const float scale =
        fmaxf(fmaxf(wmax[0], wmax[1]), fmaxf(wmax[2], wmax[3])) / 127.0f;
    if (tid == 0) xs[row] = __float2half(scale);
    uint32_t* q = (uint32_t*)(xq + base);
    #pragma unroll
    for (int i = 0; i < 4; ++i) {
      float f[4] = {v[i].x, v[i].y, v[i].z, v[i].w};
      uint32_t p = 0;
      #pragma unroll
      for (int j = 0; j < 4; ++j) {
        float r = fminf(127.0f, fmaxf(-128.0f, rintf(f[j] / scale)));
        p |= ((uint32_t)((int)r & 255)) << (8 * j);
      }
      q[i * 256 + tid] = p;
    }
    return;
  }

  // generic two-pass fallback
  float mx = 0.0f;
  if (xf32) {
    const float* x = (const float*)xin + base;
    for (int k = tid * 4; k < K; k += 256 * 4) {
      float4 v = *(const float4*)(x + k);
      mx = fmaxf(mx, fmaxf(fmaxf(fabsf(v.x), fabsf(v.y)),
                           fmaxf(fabsf(v.z), fabsf(v.w))));
    }
  } else {
    const __half* x = (const __half*)xin + base;
    for (int k = tid * 8; k < K; k += 256 * 8) {
      uint4 u = *(const uint4*)(x + k);
      const __half* hp = (const __half*)&u;
      #pragma unroll
      for (int j = 0; j < 8; ++j) mx = fmaxf(mx, fabsf(__half2float(hp[j])));
    }
  }
  #pragma unroll
  for (int off = 32; off; off >>= 1) mx = fmaxf(mx, __shfl_xor(mx, off, 64));
  if (lane == 0) wmax[wv] = mx;
  __syncthreads();
  const float scale =
      fmaxf(fmaxf(wmax[0], wmax[1]), fmaxf(wmax[2], wmax[3])) / 127.0f;
  if (tid == 0) xs[row] = __float2half(scale);

  for (int k = tid * 8; k < K; k += 256 * 8) {
    float f[8];
    if (xf32) {
      const float* x = (const float*)xin + base;
      float4 a = *(const float4*)(x + k);
      float4 b = *(const float4*)(x + k + 4);
      f[0]=a.x; f[1]=a.y; f[2]=a.z; f[3]=a.w; f[4]=b.x; f[5]=b.y; f[6]=b.z; f[7]=b.w;
    } else {
      const __half* x = (const __half*)xin + base;
      uint4 u = *(const uint4*)(x + k);
      const __half* hp = (const __half*)&u;
      #pragma unroll
      for (int j = 0; j < 8; ++j) f[j] = __half2float(hp[j]);
    }
    uint32_t p0 = 0, p1 = 0;
    #pragma unroll
    for (int j = 0; j < 4; ++j) {
      float r = fminf(127.0f, fmaxf(-128.0f, rintf(f[j] / scale)));
      p0 |= ((uint32_t)((int)r & 255)) << (8 * j);
    }
    #pragma unroll
    for (int j = 0; j < 4; ++j) {
      float r = fminf(127.0f, fmaxf(-128.0f, rintf(f[4 + j] / scale)));
      p1 |= ((uint32_t)((int)r & 255)) << (8 * j);
    }
    uint2 st; st.x = p0; st.y = p1;
    *(uint2*)(xq + base + k) = st;
  }
}

// ---------------------------------------------------------------------------
// int8 GEMM, 256x256 tile, BK=128, 8 waves (2Mx4N). A staged in LDS (r12's
// verified path: 64KiB double-buffer, swizzle chunk^=(row&7), gload_lds16);
// B READ DIRECTLY FROM GLOBAL into registers (64B-coalesced: lanes lk=0..3
// of one lr share a 64B line) -- cuts LDS reads 24->16 b128/wave/tile and
// halves LDS writes (r14 calibration: LDS pipe floor ~ MFMA floor, pipes
// serialize; removing traffic beats rescheduling it). B(t+1) issued mid-tile,
// drained by free vmcnt(0) at next tile top (~2000cyc in flight). Counted
// vmcnt(8) = stage-A done, B stays out. Two named B-sets, 2x-unrolled loop.
// Requires K % 128 == 0, K/128 >= 2 even count, M,N % 256 == 0.
// ---------------------------------------------------------------------------
__global__ __launch_bounds__(512, 2) void gemm_w8a8(
    const int8_t* __restrict__ xq, const int8_t* __restrict__ wq,
    const __half* __restrict__ xs, const float* __restrict__ wscale,
    const float* __restrict__ mos, float* __restrict__ out,
    int M, int N, int K)
{
  __shared__ int8_t sA[2][256 * 128];   // 64 KiB total

  const int tid  = threadIdx.x;
  const int lane = tid & 63;
  const int w    = tid >> 6;
  const int wr   = w >> 2;        // 0..1 -> 128 rows of C
  const int wc   = w & 3;         // 0..3 -> 64 cols of C
  const int lr   = lane & 15;
  const int lk   = lane >> 4;

  // XCD-aware swizzle (bijective: gridDim.x % 8 == 0 for our shapes)
  int L = blockIdx.x;
  const int nwg = gridDim.x;
  if ((nwg & 7) == 0) L = (L & 7) * (nwg >> 3) + (L >> 3);
  const int ntn = N >> 8;
  const int bn = (L % ntn) << 8;
  const int bm = (L / ntn) << 8;

  v4i acc[8][4];
  #pragma unroll
  for (int i = 0; i < 8; ++i)
    #pragma unroll
    for (int j = 0; j < 4; ++j) {
      v4i z = {0, 0, 0, 0};
      acc[i][j] = z;
    }

  // stage A 256x128B tile; LDS slot (r,p) holds global chunk p ^ (r&7)
  auto stageA = [&](int kt, int buf) {
    const int k0 = kt << 7;
    #pragma unroll
    for (int i = 0; i < 4; ++i) {
      const int li = i * 512 + tid;
      const int r  = li >> 3;
      const int p  = li & 7;
      const int sc = p ^ (r & 7);
      GLOAD_LDS16(xq + (size_t)(bm + r) * K + k0 + (sc << 4),
                  &sA[buf][(i * 512 + (w << 6)) << 4]);
    }
  };

  // swizzled A ds_read byte offsets (kk=0); kk=1 base = kk=0 base XOR 64
  const int rowA0 = (wr << 7) + lr;
  const int aoff0 = rowA0 * 128 + ((lk ^ (lr & 7)) << 4);
  const int aoff1 = aoff0 ^ 64;

  // per-lane B row pointer: row = bn + wc*64 + lr (+ni*16), byte lk*16 (+kk*64)
  const int8_t* wrow = wq + (size_t)(bn + (wc << 6) + lr) * K + (lk << 4);
  const size_t nstep = (size_t)16 * (size_t)K;   // ni advance

  const int nt = K >> 7;   // 32 for K=4096 (even; loop 2x-unrolled)

  // prologue: stage A(0); load B(0) into set A
  v4i b0A[4], b1A[4], b0B[4], b1B[4];
  stageA(0, 0);
  #pragma unroll
  for (int ni = 0; ni < 4; ++ni) b0A[ni] = *(const v4i*)(wrow + ni * nstep);
  #pragma unroll
  for (int ni = 0; ni < 4; ++ni) b1A[ni] = *(const v4i*)(wrow + ni * nstep + 64);
  asm volatile("s_waitcnt vmcnt(0)" ::: "memory");
  __builtin_amdgcn_s_barrier();

#define MFMA16(BASE, AV, BV)                                                 \
    __builtin_amdgcn_s_setprio(1);                                           \
    _Pragma("unroll")                                                        \
    for (int j = 0; j < 4; ++j)                                              \
      _Pragma("unroll")                                                      \
      for (int ni = 0; ni < 4; ++ni)                                         \
        acc[(BASE) + j][ni] = __builtin_amdgcn_mfma_i32_16x16x64_i8(         \
            AV[j], BV[ni], acc[(BASE) + j][ni], 0, 0, 0);                    \
    __builtin_amdgcn_s_setprio(0);

  // One K-tile. BC0/BC1 = current B regs; BN0/BN1 = next-tile B regs.
#define TILE(T, BC0, BC1, BN0, BN1)                                          \
  {                                                                          \
    const int buf = (T) & 1;                                                 \
    const int8_t* Ab = sA[buf];                                              \
    const bool ds = (T) + 1 < nt;                                            \
    const int k0n = ((T) + 1) << 7;                                          \
    v4i a0[4], a1[4];                                                        \
    asm volatile("s_waitcnt vmcnt(0)" ::: "memory"); /* BC landed (free) */  \
    _Pragma("unroll")                                                        \
    for (int j = 0; j < 4; ++j) a0[j] = *(const v4i*)(Ab + aoff0 + j * 2048);\
    if (ds) stageA((T) + 1, buf ^ 1);                                        \
    asm volatile("s_waitcnt lgkmcnt(0)" ::: "memory");                       \
    MFMA16(0, a0, BC0)                                                       \
    _Pragma("unroll")                                                        \
    for (int j = 0; j < 4; ++j)                                              \
      a1[j] = *(const v4i*)(Ab + aoff0 + 8192 + j * 2048);                   \
    if (ds) {                                                                \
      _Pragma("unroll")                                                      \
      for (int ni = 0; ni < 4; ++ni)                                         \
        BN0[ni] = *(const v4i*)(wrow + ni * nstep + k0n);                    \
    }                                                                        \
    asm volatile("s_waitcnt lgkmcnt(0)" ::: "memory");                       \
    MFMA16(4, a1, BC0)                                                       \
    _Pragma("unroll")                                                        \
    for (int j = 0; j < 4; ++j) a0[j] = *(const v4i*)(Ab + aoff1 + j * 2048);\
    if (ds) {                                                                \
      _Pragma("unroll")                                                      \
      for (int ni = 0; ni < 4; ++ni)                                         \
        BN1[ni] = *(const v4i*)(wrow + ni * nstep + k0n + 64);               \
    }                                                                        \
    asm volatile("s_waitcnt lgkmcnt(0)" ::: "memory");                       \
    MFMA16(0, a0, BC1)                                                       \
    _Pragma("unroll")                                                        \
    for (int j = 0; j < 4; ++j)                                              \
      a1[j] = *(const v4i*)(Ab + aoff1 + 8192 + j * 2048);                   \
    asm volatile("s_waitcnt lgkmcnt(0)" ::: "memory");                       \
    MFMA16(4, a1, BC1)                                                       \
    /* stage-A(t+1) done (oldest 4); 8 B-next loads stay in flight */        \
    asm volatile("s_waitcnt vmcnt(8)" ::: "memory");                         \
    __builtin_amdgcn_s_barrier();                                            \
  }

  #pragma unroll 1
  for (int t = 0; t < nt; t += 2) {
    TILE(t,     b0A, b1A, b0B, b1B)
    TILE(t + 1, b0B, b1B, b0A, b1A)
  }
#undef TILE
#undef MFMA16

  // epilogue: out = (float(half(acc*s_out)) * wscale[n]) * float(half_scale[m])
  const float s_out = mos[0];
  #pragma unroll
  for (int ni = 0; ni < 4; ++ni) {
    const int n_g = bn + (wc << 6) + ni * 16 + lr;
    const float wsc = wscale[n_g];
    #pragma unroll
    for (int mi = 0; mi < 8; ++mi) {
      #pragma unroll
      for (int j = 0; j < 4; ++j) {
        const int m_g = bm + (wr << 7) + mi * 16 + lk * 4 + j;
        const float y = __half2float(__float2half((float)acc[mi][ni][j] * s_out));
        out[(size_t)m_g * N + n_g] = (y * wsc) * __half2float(xs[m_g]);
      }
    }
  }
}

// ---------------------------------------------------------------------------
extern "C" void kernel_launch(void* const* d_in, const int* in_sizes, int n_in,
                              void* d_out, int out_size, void* d_ws, size_t ws_size,
                              hipStream_t stream) {
  const void*  x      = d_in[0];
  const void*  win    = d_in[1];
  const float* wscale = (const float*)d_in[2];
  const float* mos    = (const float*)d_in[3];
  float*       out    = (float*)d_out;

  const int N = in_sizes[2];            // 4096
  const int K = in_sizes[1] / N;        // 4096
  const int M = in_sizes[0] / K;        // 8192 (B*S)

  int8_t* xq = (int8_t*)d_ws + XQ_OFF;
  __half* xs = (__half*)((char*)d_ws + XS_OFF);
  int8_t* w8 = (int8_t*)d_ws + W8_OFF;

  prologue<<<M + RW_BLOCKS, 256, 0, stream>>>(x, win, xq, xs, w8, K, M, N * K);

  gemm_w8a8<<<dim3((M >> 8) * (N >> 8)), 512, 0, stream>>>(
      xq, w8, xs, wscale, mos, out, M, N, K);
}

// Round 16
// 187.317 us; speedup vs baseline: 2.1275x; 2.1275x over previous
//
#include <hip/hip_runtime.h>
#include <hip/hip_fp16.h>
#include <stdint.h>

typedef int v4i __attribute__((ext_vector_type(4)));

#define GLOAD_LDS16(g, l) __builtin_amdgcn_global_load_lds(                  \
    (const __attribute__((address_space(1))) void*)(g),                      \
    (__attribute__((address_space(3))) void*)(l), 16, 0, 0)

// workspace layout (bytes)
#define XQ_OFF 0u
#define XS_OFF 33554432u              // M*K int8
#define W8_OFF 33570816u              // + M*2 fp16 scales

// ---------------------------------------------------------------------------
// Self-classification of input delivery: x widened fp16->f32 has low 13
// mantissa bits zero; w widened int8->int32 has every word in [-128,127].
// ---------------------------------------------------------------------------
__device__ inline bool x_is_f32(const void* xin) {
  const uint32_t* xw = (const uint32_t*)xin;
  bool ok = true;
  #pragma unroll
  for (int i = 0; i < 16; ++i) ok &= ((xw[i] & 0x1FFFu) == 0u);
  return ok;
}
__device__ inline bool w_is_i32(const void* win) {
  const int* wi = (const int*)win;
  bool ok = true;
  #pragma unroll
  for (int i = 0; i < 16; ++i) ok &= (wi[i] >= -128 && wi[i] <= 127);
  return ok;
}

// ---------------------------------------------------------------------------
// Fused prologue: blocks [0, M) quant x rows; blocks [M, M+RW_BLOCKS) repack w.
// Both memory-bound on disjoint streams -> concurrent at full HBM BW.
// ---------------------------------------------------------------------------
#define RW_BLOCKS 1024

__global__ __launch_bounds__(256) void prologue(
    const void* __restrict__ xin, const void* __restrict__ win,
    int8_t* __restrict__ xq, __half* __restrict__ xs,
    int8_t* __restrict__ w8, int K, int M, int wtotal)
{
  const int tid = threadIdx.x;

  if (blockIdx.x >= (unsigned)M) {
    const bool as32 = w_is_i32(win);
    const int bid  = blockIdx.x - M;
    const int gtid = bid * 256 + tid;
    const int nthr = RW_BLOCKS * 256;
    if (as32) {
      const int4* w4 = (const int4*)win;
      uint32_t* dst = (uint32_t*)w8;
      const int n4 = wtotal >> 2;
      for (int i = gtid; i < n4; i += nthr) {
        int4 v = w4[i];
        dst[i] = (uint32_t)(v.x & 255) | ((uint32_t)(v.y & 255) << 8) |
                 ((uint32_t)(v.z & 255) << 16) | ((uint32_t)(v.w & 255) << 24);
      }
    } else {
      const uint4* src = (const uint4*)win;
      uint4* dst = (uint4*)w8;
      const int n16 = wtotal >> 4;
      for (int i = gtid; i < n16; i += nthr) dst[i] = src[i];
    }
    return;
  }

  const bool xf32 = x_is_f32(xin);
  const int row  = blockIdx.x;
  const int lane = tid & 63;
  const int wv   = tid >> 6;
  const size_t base = (size_t)row * (size_t)K;
  __shared__ float wmax[4];

  if (xf32 && K == 4096) {
    const float4* x4 = (const float4*)((const float*)xin + base);
    float4 v[4];
    #pragma unroll
    for (int i = 0; i < 4; ++i) v[i] = x4[i * 256 + tid];
    float mx = 0.0f;
    #pragma unroll
    for (int i = 0; i < 4; ++i)
      mx = fmaxf(mx, fmaxf(fmaxf(fabsf(v[i].x), fabsf(v[i].y)),
                           fmaxf(fabsf(v[i].z), fabsf(v[i].w))));
    #pragma unroll
    for (int off = 32; off; off >>= 1) mx = fmaxf(mx, __shfl_xor(mx, off, 64));
    if (lane == 0) wmax[wv] = mx;
    __syncthreads();
    const float scale =
        fmaxf(fmaxf(wmax[0], wmax[1]), fmaxf(wmax[2], wmax[3])) / 127.0f;
    if (tid == 0) xs[row] = __float2half(scale);
    uint32_t* q = (uint32_t*)(xq + base);
    #pragma unroll
    for (int i = 0; i < 4; ++i) {
      float f[4] = {v[i].x, v[i].y, v[i].z, v[i].w};
      uint32_t p = 0;
      #pragma unroll
      for (int j = 0; j < 4; ++j) {
        float r = fminf(127.0f, fmaxf(-128.0f, rintf(f[j] / scale)));
        p |= ((uint32_t)((int)r & 255)) << (8 * j);
      }
      q[i * 256 + tid] = p;
    }
    return;
  }

  // generic two-pass fallback
  float mx = 0.0f;
  if (xf32) {
    const float* x = (const float*)xin + base;
    for (int k = tid * 4; k < K; k += 256 * 4) {
      float4 v = *(const float4*)(x + k);
      mx = fmaxf(mx, fmaxf(fmaxf(fabsf(v.x), fabsf(v.y)),
                           fmaxf(fabsf(v.z), fabsf(v.w))));
    }
  } else {
    const __half* x = (const __half*)xin + base;
    for (int k = tid * 8; k < K; k += 256 * 8) {
      uint4 u = *(const uint4*)(x + k);
      const __half* hp = (const __half*)&u;
      #pragma unroll
      for (int j = 0; j < 8; ++j) mx = fmaxf(mx, fabsf(__half2float(hp[j])));
    }
  }
  #pragma unroll
  for (int off = 32; off; off >>= 1) mx = fmaxf(mx, __shfl_xor(mx, off, 64));
  if (lane == 0) wmax[wv] = mx;
  __syncthreads();
  const float scale =
      fmaxf(fmaxf(wmax[0], wmax[1]), fmaxf(wmax[2], wmax[3])) / 127.0f;
  if (tid == 0) xs[row] = __float2half(scale);

  for (int k = tid * 8; k < K; k += 256 * 8) {
    float f[8];
    if (xf32) {
      const float* x = (const float*)xin + base;
      float4 a = *(const float4*)(x + k);
      float4 b = *(const float4*)(x + k + 4);
      f[0]=a.x; f[1]=a.y; f[2]=a.z; f[3]=a.w; f[4]=b.x; f[5]=b.y; f[6]=b.z; f[7]=b.w;
    } else {
      const __half* x = (const __half*)xin + base;
      uint4 u = *(const uint4*)(x + k);
      const __half* hp = (const __half*)&u;
      #pragma unroll
      for (int j = 0; j < 8; ++j) f[j] = __half2float(hp[j]);
    }
    uint32_t p0 = 0, p1 = 0;
    #pragma unroll
    for (int j = 0; j < 4; ++j) {
      float r = fminf(127.0f, fmaxf(-128.0f, rintf(f[j] / scale)));
      p0 |= ((uint32_t)((int)r & 255)) << (8 * j);
    }
    #pragma unroll
    for (int j = 0; j < 4; ++j) {
      float r = fminf(127.0f, fmaxf(-128.0f, rintf(f[4 + j] / scale)));
      p1 |= ((uint32_t)((int)r & 255)) << (8 * j);
    }
    uint2 st; st.x = p0; st.y = p1;
    *(uint2*)(xq + base + k) = st;
  }
}

// ---------------------------------------------------------------------------
// int8 GEMM (verified best, r12): 256x256 tile, BK=128, 8 waves (2Mx4N),
// mfma_i32_16x16x64_i8, double-buffered LDS (128KiB), one barrier per K-tile,
// register-pipelined fragments with counted lgkmcnt, counted vmcnt (stage
// issued early, drained at tile end). Swizzle: chunk ^= (row&7) over 8
// 16B-chunks per 128B row (0 bank conflicts). K%128==0, M,N%256==0.
// ---------------------------------------------------------------------------
__global__ __launch_bounds__(512, 2) void gemm_w8a8(
    const int8_t* __restrict__ xq, const int8_t* __restrict__ wq,
    const __half* __restrict__ xs, const float* __restrict__ wscale,
    const float* __restrict__ mos, float* __restrict__ out,
    int M, int N, int K)
{
  __shared__ int8_t sA[2][256 * 128];   // 64 KiB
  __shared__ int8_t sB[2][256 * 128];   // 64 KiB

  const int tid  = threadIdx.x;
  const int lane = tid & 63;
  const int w    = tid >> 6;
  const int wr   = w >> 2;        // 0..1 -> 128 rows of C
  const int wc   = w & 3;         // 0..3 -> 64 cols of C
  const int lr   = lane & 15;
  const int lk   = lane >> 4;

  // XCD-aware swizzle (bijective: gridDim.x % 8 == 0 for our shapes)
  int L = blockIdx.x;
  const int nwg = gridDim.x;
  if ((nwg & 7) == 0) L = (L & 7) * (nwg >> 3) + (L >> 3);
  const int ntn = N >> 8;
  const int bn = (L % ntn) << 8;
  const int bm = (L / ntn) << 8;

  v4i acc[8][4];
  #pragma unroll
  for (int i = 0; i < 8; ++i)
    #pragma unroll
    for (int j = 0; j < 4; ++j) {
      v4i z = {0, 0, 0, 0};
      acc[i][j] = z;
    }

  // stage 256x128B tile; LDS slot (r,p) holds global chunk p ^ (r&7)
  auto stageA = [&](int kt, int buf) {
    const int k0 = kt << 7;
    #pragma unroll
    for (int i = 0; i < 4; ++i) {
      const int li = i * 512 + tid;
      const int r  = li >> 3;
      const int p  = li & 7;
      const int sc = p ^ (r & 7);
      GLOAD_LDS16(xq + (size_t)(bm + r) * K + k0 + (sc << 4),
                  &sA[buf][(i * 512 + (w << 6)) << 4]);
    }
  };
  auto stageB = [&](int kt, int buf) {
    const int k0 = kt << 7;
    #pragma unroll
    for (int i = 0; i < 4; ++i) {
      const int li = i * 512 + tid;
      const int r  = li >> 3;
      const int p  = li & 7;
      const int sc = p ^ (r & 7);
      GLOAD_LDS16(wq + (size_t)(bn + r) * K + k0 + (sc << 4),
                  &sB[buf][(i * 512 + (w << 6)) << 4]);
    }
  };

  // swizzled ds_read byte offsets (kk=0); kk=1 base = kk=0 base XOR 64.
  // row&7 == lr&7 for all fragment rows (row-base offsets are x16).
  const int rowA0 = (wr << 7) + lr;
  const int aoff0 = rowA0 * 128 + ((lk ^ (lr & 7)) << 4);
  const int aoff1 = aoff0 ^ 64;
  const int rowB0 = (wc << 6) + lr;
  const int boff0 = rowB0 * 128 + ((lk ^ (lr & 7)) << 4);
  const int boff1 = boff0 ^ 64;

  const int nt = K >> 7;   // 32 for K=4096

  // prologue
  stageA(0, 0); stageB(0, 0);
  asm volatile("s_waitcnt vmcnt(0)" ::: "memory");
  __builtin_amdgcn_s_barrier();

  #pragma unroll 1
  for (int t = 0; t < nt; ++t) {
    const int buf = t & 1;
    const int8_t* Ab = sA[buf];
    const int8_t* Bb = sB[buf];
    const bool do_stage = (t + 1 < nt);
    v4i a00[4], a10[4], a01[4], a11[4], b0[4], b1[4];

    // gate burst: kk=0 h0 A-frags + kk=0 B-frags (8 reads)
    #pragma unroll
    for (int j = 0; j < 4; ++j) a00[j] = *(const v4i*)(Ab + aoff0 + j * 2048);
    #pragma unroll
    for (int j = 0; j < 4; ++j) b0[j]  = *(const v4i*)(Bb + boff0 + j * 2048);

    if (do_stage) stageA(t + 1, buf ^ 1);        // 4 gloads, ~2400cyc early

    asm volatile("s_waitcnt lgkmcnt(0)" ::: "memory");
    __builtin_amdgcn_s_setprio(1);
    #pragma unroll
    for (int j = 0; j < 4; ++j)
      #pragma unroll
      for (int ni = 0; ni < 4; ++ni)
        acc[j][ni] = __builtin_amdgcn_mfma_i32_16x16x64_i8(
            a00[j], b0[ni], acc[j][ni], 0, 0, 0);
    __builtin_amdgcn_s_setprio(0);

    // under-cover burst: h1/k0 A, k1 B, h0/k1 A (12 reads, in this order)
    #pragma unroll
    for (int j = 0; j < 4; ++j) a10[j] = *(const v4i*)(Ab + aoff0 + 8192 + j * 2048);
    #pragma unroll
    for (int j = 0; j < 4; ++j) b1[j]  = *(const v4i*)(Bb + boff1 + j * 2048);
    #pragma unroll
    for (int j = 0; j < 4; ++j) a01[j] = *(const v4i*)(Ab + aoff1 + j * 2048);

    if (do_stage) stageB(t + 1, buf ^ 1);        // 4 gloads, ~1800cyc early

    asm volatile("s_waitcnt lgkmcnt(8)" ::: "memory");   // a10 landed
    __builtin_amdgcn_s_setprio(1);
    #pragma unroll
    for (int j = 0; j < 4; ++j)
      #pragma unroll
      for (int ni = 0; ni < 4; ++ni)
        acc[4 + j][ni] = __builtin_amdgcn_mfma_i32_16x16x64_i8(
            a10[j], b0[ni], acc[4 + j][ni], 0, 0, 0);
    __builtin_amdgcn_s_setprio(0);

    // last A burst (4 reads)
    #pragma unroll
    for (int j = 0; j < 4; ++j) a11[j] = *(const v4i*)(Ab + aoff1 + 8192 + j * 2048);

    asm volatile("s_waitcnt lgkmcnt(4)" ::: "memory");   // b1,a01 landed
    __builtin_amdgcn_s_setprio(1);
    #pragma unroll
    for (int j = 0; j < 4; ++j)
      #pragma unroll
      for (int ni = 0; ni < 4; ++ni)
        acc[j][ni] = __builtin_amdgcn_mfma_i32_16x16x64_i8(
            a01[j], b1[ni], acc[j][ni], 0, 0, 0);
    __builtin_amdgcn_s_setprio(0);

    asm volatile("s_waitcnt lgkmcnt(0)" ::: "memory");   // a11 landed
    __builtin_amdgcn_s_setprio(1);
    #pragma unroll
    for (int j = 0; j < 4; ++j)
      #pragma unroll
      for (int ni = 0; ni < 4; ++ni)
        acc[4 + j][ni] = __builtin_amdgcn_mfma_i32_16x16x64_i8(
            a11[j], b1[ni], acc[4 + j][ni], 0, 0, 0);
    __builtin_amdgcn_s_setprio(0);

    // stage(t+1) must be fully resident before next iter's reads
    asm volatile("s_waitcnt vmcnt(0)" ::: "memory");
    __builtin_amdgcn_s_barrier();
  }

  // epilogue: out = (float(half(acc*s_out)) * wscale[n]) * float(half_scale[m])
  const float s_out = mos[0];
  #pragma unroll
  for (int ni = 0; ni < 4; ++ni) {
    const int n_g = bn + (wc << 6) + ni * 16 + lr;
    const float wsc = wscale[n_g];
    #pragma unroll
    for (int mi = 0; mi < 8; ++mi) {
      #pragma unroll
      for (int j = 0; j < 4; ++j) {
        const int m_g = bm + (wr << 7) + mi * 16 + lk * 4 + j;
        const float y = __half2float(__float2half((float)acc[mi][ni][j] * s_out));
        out[(size_t)m_g * N + n_g] = (y * wsc) * __half2float(xs[m_g]);
      }
    }
  }
}

// ---------------------------------------------------------------------------
extern "C" void kernel_launch(void* const* d_in, const int* in_sizes, int n_in,
                              void* d_out, int out_size, void* d_ws, size_t ws_size,
                              hipStream_t stream) {
  const void*  x      = d_in[0];
  const void*  win    = d_in[1];
  const float* wscale = (const float*)d_in[2];
  const float* mos    = (const float*)d_in[3];
  float*       out    = (float*)d_out;

  const int N = in_sizes[2];            // 4096
  const int K = in_sizes[1] / N;        // 4096
  const int M = in_sizes[0] / K;        // 8192 (B*S)

  int8_t* xq = (int8_t*)d_ws + XQ_OFF;
  __half* xs = (__half*)((char*)d_ws + XS_OFF);
  int8_t* w8 = (int8_t*)d_ws + W8_OFF;

  prologue<<<M + RW_BLOCKS, 256, 0, stream>>>(x, win, xq, xs, w8, K, M, N * K);

  gemm_w8a8<<<dim3((M >> 8) * (N >> 8)), 512, 0, stream>>>(
      xq, w8, xs, wscale, mos, out, M, N, K);
}